// Round 3
// baseline (130.167 us; speedup 1.0000x reference)
//
#include <hip/hip_runtime.h>
#include <stdint.h>

#define B_ 64
#define K_ 8192
#define O_ 8192
#define R_ 64
#define KS 8            // K-split ways
#define KSL (K_ / KS)   // 1024 per split
#define BK 64           // K per step
#define NS (KSL / BK)   // 16 steps per wave

typedef __attribute__((ext_vector_type(8))) short s16x8;   // 8 bf16
typedef __attribute__((ext_vector_type(4))) float f32x4;

// round-to-nearest-even f32 -> bf16, packed pair
__device__ __forceinline__ uint32_t rne_pack(float a, float b) {
  uint32_t ua = __float_as_uint(a), ub = __float_as_uint(b);
  ua += 0x7fffu + ((ua >> 16) & 1u);
  ub += 0x7fffu + ((ub >> 16) & 1u);
  return (ua >> 16) | (ub & 0xffff0000u);
}

// (w - 128) in [-128,127]: EXACT in bf16, truncation suffices
__device__ __forceinline__ uint32_t wpack(int w0, int w1) {
  float f0 = (float)(w0 - 128);
  float f1 = (float)(w1 - 128);
  return (__float_as_uint(f0) >> 16) | (__float_as_uint(f1) & 0xffff0000u);
}

__device__ __forceinline__ s16x8 bfrag_from(int4 a, int4 b) {
  union { uint32_t u[4]; s16x8 v; } r;
  r.u[0] = wpack(a.x, a.y); r.u[1] = wpack(a.z, a.w);
  r.u[2] = wpack(b.x, b.y); r.u[3] = wpack(b.z, b.w);
  return r.v;
}

__device__ __forceinline__ s16x8 afrag(uint4 x) {
  union { uint4 u; s16x8 v; } r; r.u = x; return r.v;
}

// ---------------------------------------------------------------------------
// k_prep: (a) x (fp32) -> bf16 xbg, row-major (all 256 blocks)
//         (b) blocks 0..63: partial mid = x @ lora_A^T over a 128-wide K slab,
//             accumulated via fp32 atomicAdd (mid zeroed by memset).
// ---------------------------------------------------------------------------
__global__ __launch_bounds__(256) void k_prep(
    const float* __restrict__ x, const float* __restrict__ lora_A,
    uint16_t* __restrict__ xbg, float* __restrict__ mid) {
  const int t = threadIdx.x;
  const int blk = blockIdx.x;

  {  // x -> bf16, 2048 elems per block, 8 per thread
    const size_t base = (size_t)blk * 2048 + (size_t)t * 8;
    float4 v0 = *(const float4*)(x + base);
    float4 v1 = *(const float4*)(x + base + 4);
    uint4 p;
    p.x = rne_pack(v0.x, v0.y);
    p.y = rne_pack(v0.z, v0.w);
    p.z = rne_pack(v1.x, v1.y);
    p.w = rne_pack(v1.z, v1.w);
    *(uint4*)(xbg + base) = p;
  }

  if (blk >= 64) return;

  __shared__ float xs[64][133];
  __shared__ float as_[64][133];
  const int kr0 = blk * 128;
  const int row = t >> 2, seg = t & 3;
#pragma unroll
  for (int j = 0; j < 8; ++j) {
    const int c = seg * 32 + j * 4;
    float4 vx = *(const float4*)(x + (size_t)row * K_ + kr0 + c);
    float4 va = *(const float4*)(lora_A + (size_t)row * K_ + kr0 + c);
    xs[row][c] = vx.x; xs[row][c + 1] = vx.y; xs[row][c + 2] = vx.z; xs[row][c + 3] = vx.w;
    as_[row][c] = va.x; as_[row][c + 1] = va.y; as_[row][c + 2] = va.z; as_[row][c + 3] = va.w;
  }
  __syncthreads();

  const int bg = t >> 4, rg = t & 15;
  const int b0 = bg * 4, r0 = rg * 4;
  float acc[4][4];
#pragma unroll
  for (int i = 0; i < 4; ++i)
#pragma unroll
    for (int j = 0; j < 4; ++j) acc[i][j] = 0.f;

  for (int k = 0; k < 128; ++k) {
    float xv[4], av[4];
#pragma unroll
    for (int i = 0; i < 4; ++i) xv[i] = xs[b0 + i][k];
#pragma unroll
    for (int j = 0; j < 4; ++j) av[j] = as_[r0 + j][k];
#pragma unroll
    for (int i = 0; i < 4; ++i)
#pragma unroll
      for (int j = 0; j < 4; ++j) acc[i][j] += xv[i] * av[j];
  }

#pragma unroll
  for (int i = 0; i < 4; ++i)
#pragma unroll
    for (int j = 0; j < 4; ++j)
      atomicAdd(&mid[(b0 + i) * R_ + (r0 + j)], acc[i][j]);
}

// ---------------------------------------------------------------------------
// k_main: barrier-free. 4096 independent waves; wave = (ks, oc) owns output
// cols oc*16..+15 x all 64 rows x K-slice [ks*1024, +1024). No LDS. 2-deep
// register double-buffer, BK=64, fully unrolled (all offsets -> immediates).
// W int32 loaded direct to regs, converted to bf16 at use. x bf16 from xbg
// (L2-resident). Raw partial sums -> part[ks][64][8192].
// ---------------------------------------------------------------------------
__global__ __launch_bounds__(256, 2) void k_main(
    const int* __restrict__ Wq, const uint16_t* __restrict__ xbg,
    float* __restrict__ part) {
  const int t = threadIdx.x;
  const int w = blockIdx.x * 4 + (t >> 6);
  const int lane = t & 63;
  const int il = lane & 15;
  const int g = lane >> 4;
  const int ks = w >> 9;   // 0..7  (same for all 4 waves of a block)
  const int oc = w & 511;  // 0..511 (4 consecutive per block -> contiguous W band)
  const int o0 = oc * 16;
  const int k0 = ks * KSL;

  const int* wp = Wq + (size_t)(o0 + il) * K_ + k0 + g * 8;
  const uint16_t* xp0 = xbg + (size_t)(il) * K_ + k0 + g * 8;
  const uint16_t* xp1 = xbg + (size_t)(16 + il) * K_ + k0 + g * 8;
  const uint16_t* xp2 = xbg + (size_t)(32 + il) * K_ + k0 + g * 8;
  const uint16_t* xp3 = xbg + (size_t)(48 + il) * K_ + k0 + g * 8;

  f32x4 ac0 = {0.f,0.f,0.f,0.f}, ac1 = {0.f,0.f,0.f,0.f};
  f32x4 ac2 = {0.f,0.f,0.f,0.f}, ac3 = {0.f,0.f,0.f,0.f};

  // named register banks (all indices compile-time; rule #20)
  int4 rw00a, rw00b, rw01a, rw01b, rw10a, rw10b, rw11a, rw11b;
  uint4 rx000, rx001, rx010, rx011, rx020, rx021, rx030, rx031;
  uint4 rx100, rx101, rx110, rx111, rx120, rx121, rx130, rx131;

#define LOADS(P, S)                                                   \
  do {                                                                \
    const int c0 = (S) * BK, c1 = (S) * BK + 32;                      \
    rw##P##0a = *(const int4*)(wp + c0);                              \
    rw##P##0b = *(const int4*)(wp + c0 + 4);                          \
    rw##P##1a = *(const int4*)(wp + c1);                              \
    rw##P##1b = *(const int4*)(wp + c1 + 4);                          \
    rx##P##00 = *(const uint4*)(xp0 + c0);                            \
    rx##P##01 = *(const uint4*)(xp0 + c1);                            \
    rx##P##10 = *(const uint4*)(xp1 + c0);                            \
    rx##P##11 = *(const uint4*)(xp1 + c1);                            \
    rx##P##20 = *(const uint4*)(xp2 + c0);                            \
    rx##P##21 = *(const uint4*)(xp2 + c1);                            \
    rx##P##30 = *(const uint4*)(xp3 + c0);                            \
    rx##P##31 = *(const uint4*)(xp3 + c1);                            \
  } while (0)

#define MFMAS(P)                                                               \
  do {                                                                         \
    s16x8 bf0 = bfrag_from(rw##P##0a, rw##P##0b);                              \
    ac0 = __builtin_amdgcn_mfma_f32_16x16x32_bf16(afrag(rx##P##00), bf0, ac0, 0, 0, 0); \
    ac1 = __builtin_amdgcn_mfma_f32_16x16x32_bf16(afrag(rx##P##10), bf0, ac1, 0, 0, 0); \
    ac2 = __builtin_amdgcn_mfma_f32_16x16x32_bf16(afrag(rx##P##20), bf0, ac2, 0, 0, 0); \
    ac3 = __builtin_amdgcn_mfma_f32_16x16x32_bf16(afrag(rx##P##30), bf0, ac3, 0, 0, 0); \
    s16x8 bf1 = bfrag_from(rw##P##1a, rw##P##1b);                              \
    ac0 = __builtin_amdgcn_mfma_f32_16x16x32_bf16(afrag(rx##P##01), bf1, ac0, 0, 0, 0); \
    ac1 = __builtin_amdgcn_mfma_f32_16x16x32_bf16(afrag(rx##P##11), bf1, ac1, 0, 0, 0); \
    ac2 = __builtin_amdgcn_mfma_f32_16x16x32_bf16(afrag(rx##P##21), bf1, ac2, 0, 0, 0); \
    ac3 = __builtin_amdgcn_mfma_f32_16x16x32_bf16(afrag(rx##P##31), bf1, ac3, 0, 0, 0); \
  } while (0)

  LOADS(0, 0);
  LOADS(1, 1);

#pragma unroll
  for (int s = 0; s < NS; s += 2) {
    MFMAS(0);
    if (s + 2 < NS) LOADS(0, s + 2);
    MFMAS(1);
    if (s + 3 < NS) LOADS(1, s + 3);
  }
#undef LOADS
#undef MFMAS

  // partial store: C/D layout col=il, row(within 16)=g*4+j
  float* pp = part + (size_t)ks * (B_ * O_) + o0 + il;
#pragma unroll
  for (int j = 0; j < 4; ++j) {
    const int r = g * 4 + j;
    pp[(size_t)(r) * O_]      = ac0[j];
    pp[(size_t)(16 + r) * O_] = ac1[j];
    pp[(size_t)(32 + r) * O_] = ac2[j];
    pp[(size_t)(48 + r) * O_] = ac3[j];
  }
}

// ---------------------------------------------------------------------------
// k_fin: out = scale * (sum of 8 partials) + bias + 0.25 * (mid @ lora_B^T).
// LoRA via the proven 2-MFMA block. 512 blocks x 16 cols, 4 waves x 16 rows.
// ---------------------------------------------------------------------------
__global__ __launch_bounds__(256) void k_fin(
    const float* __restrict__ part, const float* __restrict__ scale,
    const float* __restrict__ lora_B, const float* __restrict__ bias,
    const float* __restrict__ mid, float* __restrict__ out) {
  __shared__ uint16_t midb[64][72];
  __shared__ uint16_t lob[16][72];

  const int t = threadIdx.x;
  const int o0 = blockIdx.x * 16;
  const int wave = t >> 6;
  const int lane = t & 63;
  const int il = lane & 15;
  const int g = lane >> 4;
  const int m0 = wave * 16;

  {  // stage mid (all threads) + lora_B tile (threads 0..63) as bf16
    const int row = t >> 2;
    const int r0 = (t & 3) * 16;
    const float* mp = mid + row * R_ + r0;
    float4 a0 = *(const float4*)(mp);
    float4 a1 = *(const float4*)(mp + 4);
    float4 a2 = *(const float4*)(mp + 8);
    float4 a3 = *(const float4*)(mp + 12);
    uint4 p0, p1;
    p0.x = rne_pack(a0.x, a0.y); p0.y = rne_pack(a0.z, a0.w);
    p0.z = rne_pack(a1.x, a1.y); p0.w = rne_pack(a1.z, a1.w);
    p1.x = rne_pack(a2.x, a2.y); p1.y = rne_pack(a2.z, a2.w);
    p1.z = rne_pack(a3.x, a3.y); p1.w = rne_pack(a3.z, a3.w);
    *(uint4*)&midb[row][r0] = p0;
    *(uint4*)&midb[row][r0 + 8] = p1;
    if (t < 64) {
      const int row2 = t >> 2;
      const float* lp = lora_B + (size_t)(o0 + row2) * R_ + r0;
      float4 c0 = *(const float4*)(lp);
      float4 c1 = *(const float4*)(lp + 4);
      float4 c2 = *(const float4*)(lp + 8);
      float4 c3 = *(const float4*)(lp + 12);
      uint4 q0, q1;
      q0.x = rne_pack(c0.x, c0.y); q0.y = rne_pack(c0.z, c0.w);
      q0.z = rne_pack(c1.x, c1.y); q0.w = rne_pack(c1.z, c1.w);
      q1.x = rne_pack(c2.x, c2.y); q1.y = rne_pack(c2.z, c2.w);
      q1.z = rne_pack(c3.x, c3.y); q1.w = rne_pack(c3.z, c3.w);
      *(uint4*)&lob[row2][r0] = q0;
      *(uint4*)&lob[row2][r0 + 8] = q1;
    }
  }
  __syncthreads();

  f32x4 acc2 = {0.f, 0.f, 0.f, 0.f};
#pragma unroll
  for (int kf = 0; kf < 2; ++kf) {
    s16x8 am = *(const s16x8*)&midb[m0 + il][kf * 32 + g * 8];
    s16x8 bl = *(const s16x8*)&lob[il][kf * 32 + g * 8];
    acc2 = __builtin_amdgcn_mfma_f32_16x16x32_bf16(am, bl, acc2, 0, 0, 0);
  }

  const float sc = scale[o0 + il];
  const float bi = bias[o0 + il];

#pragma unroll
  for (int j = 0; j < 4; ++j) {
    const int b = m0 + g * 4 + j;
    const size_t idx = (size_t)b * O_ + o0 + il;
    float s = 0.f;
#pragma unroll
    for (int k = 0; k < KS; ++k) s += part[(size_t)k * (B_ * O_) + idx];
    out[idx] = sc * s + bi + 0.25f * acc2[j];
  }
}

// ---------------------------------------------------------------------------
extern "C" void kernel_launch(void* const* d_in, const int* in_sizes, int n_in,
                              void* d_out, int out_size, void* d_ws, size_t ws_size,
                              hipStream_t stream) {
  const float* x = (const float*)d_in[0];
  const int* Wq = (const int*)d_in[1];
  const float* scale = (const float*)d_in[2];
  const float* lora_A = (const float*)d_in[3];
  const float* lora_B = (const float*)d_in[4];
  const float* bias = (const float*)d_in[5];
  float* out = (float*)d_out;

  uint16_t* xbg = (uint16_t*)d_ws;                            // 1 MiB bf16 x
  float* mid = (float*)((char*)d_ws + (2u << 20));            // 16 KiB fp32
  float* part = (float*)((char*)d_ws + (4u << 20));           // 16 MiB fp32

  hipMemsetAsync(mid, 0, B_ * R_ * sizeof(float), stream);
  k_prep<<<256, 256, 0, stream>>>(x, lora_A, xbg, mid);
  k_main<<<(KS * (O_ / 16)) / 4, 256, 0, stream>>>(Wq, xbg, part);
  k_fin<<<O_ / 16, 256, 0, stream>>>(part, scale, lora_B, bias, mid, out);
}

// Round 4
// 103.363 us; speedup vs baseline: 1.2593x; 1.2593x over previous
//
#include <hip/hip_runtime.h>
#include <stdint.h>

#define B_ 64
#define K_ 8192
#define O_ 8192
#define R_ 64
#define NT 16
#define KSP 2             // K-split ways
#define KHALF (K_ / KSP)  // 4096
#define BK 128            // K per step
#define NS2 (KHALF / BK)  // 32 steps

typedef __attribute__((ext_vector_type(8))) short s16x8;   // 8 bf16
typedef __attribute__((ext_vector_type(4))) float f32x4;

// round-to-nearest-even f32 -> bf16, packed pair
__device__ __forceinline__ uint32_t rne_pack(float a, float b) {
  uint32_t ua = __float_as_uint(a), ub = __float_as_uint(b);
  ua += 0x7fffu + ((ua >> 16) & 1u);
  ub += 0x7fffu + ((ub >> 16) & 1u);
  return (ua >> 16) | (ub & 0xffff0000u);
}

// (w - 128) in [-128,127]: EXACT in bf16, truncation suffices
__device__ __forceinline__ uint32_t wpack(int w0, int w1) {
  float f0 = (float)(w0 - 128);
  float f1 = (float)(w1 - 128);
  return (__float_as_uint(f0) >> 16) | (__float_as_uint(f1) & 0xffff0000u);
}

__device__ __forceinline__ s16x8 afrag(uint4 x) {
  union { uint4 u; s16x8 v; } r; r.u = x; return r.v;
}

// ---------------------------------------------------------------------------
// k_prep: (a) x (fp32) -> bf16 xbg (all 256 blocks)
//         (b) blocks 0..63: partial mid = x @ lora_A^T over a 128-wide K slab,
//             accumulated via fp32 atomicAdd (mid zeroed by memset).
// ---------------------------------------------------------------------------
__global__ __launch_bounds__(256) void k_prep(
    const float* __restrict__ x, const float* __restrict__ lora_A,
    uint16_t* __restrict__ xbg, float* __restrict__ mid) {
  const int t = threadIdx.x;
  const int blk = blockIdx.x;

  {  // x -> bf16, 2048 elems per block, 8 per thread
    const size_t base = (size_t)blk * 2048 + (size_t)t * 8;
    float4 v0 = *(const float4*)(x + base);
    float4 v1 = *(const float4*)(x + base + 4);
    uint4 p;
    p.x = rne_pack(v0.x, v0.y);
    p.y = rne_pack(v0.z, v0.w);
    p.z = rne_pack(v1.x, v1.y);
    p.w = rne_pack(v1.z, v1.w);
    *(uint4*)(xbg + base) = p;
  }

  if (blk >= 64) return;

  __shared__ float xs[64][133];
  __shared__ float as_[64][133];
  const int kr0 = blk * 128;
  const int row = t >> 2, seg = t & 3;
#pragma unroll
  for (int j = 0; j < 8; ++j) {
    const int c = seg * 32 + j * 4;
    float4 vx = *(const float4*)(x + (size_t)row * K_ + kr0 + c);
    float4 va = *(const float4*)(lora_A + (size_t)row * K_ + kr0 + c);
    xs[row][c] = vx.x; xs[row][c + 1] = vx.y; xs[row][c + 2] = vx.z; xs[row][c + 3] = vx.w;
    as_[row][c] = va.x; as_[row][c + 1] = va.y; as_[row][c + 2] = va.z; as_[row][c + 3] = va.w;
  }
  __syncthreads();

  const int bg = t >> 4, rg = t & 15;
  const int b0 = bg * 4, r0 = rg * 4;
  float acc[4][4];
#pragma unroll
  for (int i = 0; i < 4; ++i)
#pragma unroll
    for (int j = 0; j < 4; ++j) acc[i][j] = 0.f;

  for (int k = 0; k < 128; ++k) {
    float xv[4], av[4];
#pragma unroll
    for (int i = 0; i < 4; ++i) xv[i] = xs[b0 + i][k];
#pragma unroll
    for (int j = 0; j < 4; ++j) av[j] = as_[r0 + j][k];
#pragma unroll
    for (int i = 0; i < 4; ++i)
#pragma unroll
      for (int j = 0; j < 4; ++j) acc[i][j] += xv[i] * av[j];
  }

#pragma unroll
  for (int i = 0; i < 4; ++i)
#pragma unroll
    for (int j = 0; j < 4; ++j)
      atomicAdd(&mid[(b0 + i) * R_ + (r0 + j)], acc[i][j]);
}

// ---------------------------------------------------------------------------
// k_main: 1024 blocks = (oc 0..511) x (ks 0..1). Per block: 16 output cols,
// all 64 batch rows, K-half of 4096. LDS = W tile only (double-buffered,
// stride 132 -> 2-way max bank aliasing = free). W: 4-deep named register
// banks, prefetch issued BEFORE a raw s_barrier (lgkmcnt-only wait -> global
// loads stay in flight across barriers). x: wave-private, direct from
// L2-resident xbg, 2-deep banks. 4 MFMAs/wave/step.
// ---------------------------------------------------------------------------
__global__ __launch_bounds__(256, 4) void k_main(
    const int* __restrict__ Wq, const uint16_t* __restrict__ xbg,
    float* __restrict__ part) {
  __shared__ uint16_t wbs[2][NT][132];

  const int t = threadIdx.x;
  const int oc = blockIdx.x >> 1;
  const int ks = blockIdx.x & 1;
  const int o0 = oc * NT;
  const int k0 = ks * KHALF;

  const int wave = t >> 6, lane = t & 63, il = lane & 15, g = lane >> 4;
  const int m0 = wave * 16;
  const int wrow = t >> 4, wseg = t & 15;

  const int* wsrc = Wq + (size_t)(o0 + wrow) * K_ + k0 + wseg * 8;
  const uint16_t* xq = xbg + (size_t)(m0 + il) * K_ + k0 + g * 8;

  // named register banks (all indices compile-time; rule #20)
  int4 rwa0, rwb0, rwa1, rwb1, rwa2, rwb2, rwa3, rwb3;
  uint4 ax00, ax01, ax02, ax03, ax10, ax11, ax12, ax13;

#define LOADW(P, S)                                  \
  do {                                               \
    rwa##P = *(const int4*)(wsrc + (S)*BK);          \
    rwb##P = *(const int4*)(wsrc + (S)*BK + 4);      \
  } while (0)
#define LOADX(Q, S)                                  \
  do {                                               \
    ax##Q##0 = *(const uint4*)(xq + (S)*BK);         \
    ax##Q##1 = *(const uint4*)(xq + (S)*BK + 32);    \
    ax##Q##2 = *(const uint4*)(xq + (S)*BK + 64);    \
    ax##Q##3 = *(const uint4*)(xq + (S)*BK + 96);    \
  } while (0)

  f32x4 acc = {0.f, 0.f, 0.f, 0.f};

  // prologue: 4 W banks + 2 x banks in flight
  LOADW(0, 0); LOADW(1, 1); LOADW(2, 2); LOADW(3, 3);
  LOADX(0, 0); LOADX(1, 1);

  // Phase: ds_write bank P -> LDS[S&1]; issue W prefetch (S+4) BEFORE the
  // barrier (stays in flight: only lgkmcnt is drained); raw barrier; 4 MFMAs
  // from LDS + x bank Q; then x prefetch (S+2) after its regs are consumed.
#define PHASE(P, Q)                                                            \
  do {                                                                         \
    const int S = s + P;                                                       \
    uint4 wv;                                                                  \
    wv.x = wpack(rwa##P.x, rwa##P.y); wv.y = wpack(rwa##P.z, rwa##P.w);        \
    wv.z = wpack(rwb##P.x, rwb##P.y); wv.w = wpack(rwb##P.z, rwb##P.w);        \
    *(uint4*)&wbs[S & 1][wrow][wseg * 8] = wv;                                 \
    if (S + 4 < NS2) LOADW(P, S + 4);                                          \
    asm volatile("s_waitcnt lgkmcnt(0)" ::: "memory");                         \
    __builtin_amdgcn_s_barrier();                                              \
    __builtin_amdgcn_sched_barrier(0);                                         \
    s16x8 bf0 = *(const s16x8*)&wbs[S & 1][il][0 * 32 + g * 8];                \
    acc = __builtin_amdgcn_mfma_f32_16x16x32_bf16(afrag(ax##Q##0), bf0, acc, 0, 0, 0); \
    s16x8 bf1 = *(const s16x8*)&wbs[S & 1][il][1 * 32 + g * 8];                \
    acc = __builtin_amdgcn_mfma_f32_16x16x32_bf16(afrag(ax##Q##1), bf1, acc, 0, 0, 0); \
    s16x8 bf2 = *(const s16x8*)&wbs[S & 1][il][2 * 32 + g * 8];                \
    acc = __builtin_amdgcn_mfma_f32_16x16x32_bf16(afrag(ax##Q##2), bf2, acc, 0, 0, 0); \
    s16x8 bf3 = *(const s16x8*)&wbs[S & 1][il][3 * 32 + g * 8];                \
    acc = __builtin_amdgcn_mfma_f32_16x16x32_bf16(afrag(ax##Q##3), bf3, acc, 0, 0, 0); \
    if (S + 2 < NS2) LOADX(Q, S + 2);                                          \
  } while (0)

  for (int s = 0; s < NS2; s += 4) {
    PHASE(0, 0);
    PHASE(1, 1);
    PHASE(2, 0);
    PHASE(3, 1);
  }
#undef LOADW
#undef LOADX
#undef PHASE

  // partial store: C/D layout col=il, batch row = m0 + g*4 + j
  float* pp = part + (size_t)ks * (B_ * O_) + o0 + il;
#pragma unroll
  for (int j = 0; j < 4; ++j)
    pp[(size_t)(m0 + g * 4 + j) * O_] = acc[j];
}

// ---------------------------------------------------------------------------
// k_fin: out = scale * (part[0] + part[1]) + bias + 0.25 * (mid @ lora_B^T).
// ---------------------------------------------------------------------------
__global__ __launch_bounds__(256) void k_fin(
    const float* __restrict__ part, const float* __restrict__ scale,
    const float* __restrict__ lora_B, const float* __restrict__ bias,
    const float* __restrict__ mid, float* __restrict__ out) {
  __shared__ uint16_t midb[64][72];
  __shared__ uint16_t lob[16][72];

  const int t = threadIdx.x;
  const int o0 = blockIdx.x * 16;
  const int wave = t >> 6;
  const int lane = t & 63;
  const int il = lane & 15;
  const int g = lane >> 4;
  const int m0 = wave * 16;

  {  // stage mid (all threads) + lora_B tile (threads 0..63) as bf16
    const int row = t >> 2;
    const int r0 = (t & 3) * 16;
    const float* mp = mid + row * R_ + r0;
    float4 a0 = *(const float4*)(mp);
    float4 a1 = *(const float4*)(mp + 4);
    float4 a2 = *(const float4*)(mp + 8);
    float4 a3 = *(const float4*)(mp + 12);
    uint4 p0, p1;
    p0.x = rne_pack(a0.x, a0.y); p0.y = rne_pack(a0.z, a0.w);
    p0.z = rne_pack(a1.x, a1.y); p0.w = rne_pack(a1.z, a1.w);
    p1.x = rne_pack(a2.x, a2.y); p1.y = rne_pack(a2.z, a2.w);
    p1.z = rne_pack(a3.x, a3.y); p1.w = rne_pack(a3.z, a3.w);
    *(uint4*)&midb[row][r0] = p0;
    *(uint4*)&midb[row][r0 + 8] = p1;
    if (t < 64) {
      const int row2 = t >> 2;
      const float* lp = lora_B + (size_t)(o0 + row2) * R_ + r0;
      float4 c0 = *(const float4*)(lp);
      float4 c1 = *(const float4*)(lp + 4);
      float4 c2 = *(const float4*)(lp + 8);
      float4 c3 = *(const float4*)(lp + 12);
      uint4 q0, q1;
      q0.x = rne_pack(c0.x, c0.y); q0.y = rne_pack(c0.z, c0.w);
      q0.z = rne_pack(c1.x, c1.y); q0.w = rne_pack(c1.z, c1.w);
      q1.x = rne_pack(c2.x, c2.y); q1.y = rne_pack(c2.z, c2.w);
      q1.z = rne_pack(c3.x, c3.y); q1.w = rne_pack(c3.z, c3.w);
      *(uint4*)&lob[row2][r0] = q0;
      *(uint4*)&lob[row2][r0 + 8] = q1;
    }
  }
  __syncthreads();

  f32x4 acc2 = {0.f, 0.f, 0.f, 0.f};
#pragma unroll
  for (int kf = 0; kf < 2; ++kf) {
    s16x8 am = *(const s16x8*)&midb[m0 + il][kf * 32 + g * 8];
    s16x8 bl = *(const s16x8*)&lob[il][kf * 32 + g * 8];
    acc2 = __builtin_amdgcn_mfma_f32_16x16x32_bf16(am, bl, acc2, 0, 0, 0);
  }

  const float sc = scale[o0 + il];
  const float bi = bias[o0 + il];

#pragma unroll
  for (int j = 0; j < 4; ++j) {
    const int b = m0 + g * 4 + j;
    const size_t idx = (size_t)b * O_ + o0 + il;
    float s = part[idx] + part[(size_t)(B_ * O_) + idx];
    out[idx] = sc * s + bi + 0.25f * acc2[j];
  }
}

// ---------------------------------------------------------------------------
extern "C" void kernel_launch(void* const* d_in, const int* in_sizes, int n_in,
                              void* d_out, int out_size, void* d_ws, size_t ws_size,
                              hipStream_t stream) {
  const float* x = (const float*)d_in[0];
  const int* Wq = (const int*)d_in[1];
  const float* scale = (const float*)d_in[2];
  const float* lora_A = (const float*)d_in[3];
  const float* lora_B = (const float*)d_in[4];
  const float* bias = (const float*)d_in[5];
  float* out = (float*)d_out;

  uint16_t* xbg = (uint16_t*)d_ws;                    // 1 MiB bf16 x
  float* mid = (float*)((char*)d_ws + (2u << 20));    // 16 KiB fp32
  float* part = (float*)((char*)d_ws + (4u << 20));   // 4 MiB fp32

  hipMemsetAsync(mid, 0, B_ * R_ * sizeof(float), stream);
  k_prep<<<256, 256, 0, stream>>>(x, lora_A, xbg, mid);
  k_main<<<KSP * (O_ / NT), 256, 0, stream>>>(Wq, xbg, part);
  k_fin<<<O_ / 16, 256, 0, stream>>>(part, scale, lora_B, bias, mid, out);
}